// Round 2
// baseline (356.306 us; speedup 1.0000x reference)
//
#include <hip/hip_runtime.h>

#define NUM_CLS   131072
#define NUM_NODE  70
#define DRUG_NUM  38
#define NSEG      140
#define ROWLEN    70
#define FEA       128
#define MTOT      524288
#define BATCH     8192
#define NB1       728                    // partial-sum blocks (3/CU LDS-resident)
#define EPB       ((MTOT + NB1 - 1) / NB1)   // 721 entries per block
#define CHUNK     512
#define SEGW      (NSEG*ROWLEN + NSEG)   // 9940 floats per partial slab
#define RCH       (NB1 / 8)              // 91 slabs per reduce1 group

// ---------------- K1: per-block partial segment sums of DTH rows ----------------
__global__ __launch_bounds__(512) void seg_partial_k(
    const float* __restrict__ dth_cls, const float* __restrict__ dth_dc,
    const int* __restrict__ he_node, const int* __restrict__ he_edge,
    float* __restrict__ partial)
{
  __shared__ float acc[NSEG * ROWLEN];   // 39200 B
  __shared__ float cnt[NSEG];
  __shared__ int   sseg[CHUNK];
  __shared__ int   soff[CHUNK];
  const int tid = threadIdx.x;
  for (int i = tid; i < NSEG * ROWLEN; i += 512) acc[i] = 0.f;
  if (tid < NSEG) cnt[tid] = 0.f;
  __syncthreads();

  const int b  = blockIdx.x;
  const int e0 = b * EPB;
  const int e1 = (e0 + EPB < MTOT) ? e0 + EPB : MTOT;
  const int wid = tid >> 6, lane = tid & 63;

  for (int c0 = e0; c0 < e1; c0 += CHUNK) {
    const int n = (e1 - c0 < CHUNK) ? (e1 - c0) : CHUNK;
    if (tid < n) {                       // coalesced bulk index prefetch
      const int node = he_node[c0 + tid];
      const int edge = he_edge[c0 + tid];
      const int isdc = (edge >= NUM_CLS);
      const int seg  = node * 2 + isdc;
      sseg[tid] = seg;
      soff[tid] = (isdc ? edge - NUM_CLS : edge) * ROWLEN;
      atomicAdd(&cnt[seg], 1.f);
    }
    __syncthreads();

    const int i0   = wid * 64;
    const int iend = (i0 + 64 < n) ? i0 + 64 : n;
    int i = i0;
    for (; i + 4 <= iend; i += 4) {      // 4 rows in flight per wave
      const int s0 = sseg[i+0], s1 = sseg[i+1], s2 = sseg[i+2], s3 = sseg[i+3];
      const float* r0 = ((s0 & 1) ? dth_dc : dth_cls) + soff[i+0];
      const float* r1 = ((s1 & 1) ? dth_dc : dth_cls) + soff[i+1];
      const float* r2 = ((s2 & 1) ? dth_dc : dth_cls) + soff[i+2];
      const float* r3 = ((s3 & 1) ? dth_dc : dth_cls) + soff[i+3];
      const float a0 = r0[lane], a1 = r1[lane], a2 = r2[lane], a3 = r3[lane];
      float b0 = 0.f, b1 = 0.f, b2 = 0.f, b3 = 0.f;
      if (lane < 6) { b0 = r0[64+lane]; b1 = r1[64+lane]; b2 = r2[64+lane]; b3 = r3[64+lane]; }
      atomicAdd(&acc[s0 * ROWLEN + lane], a0);
      atomicAdd(&acc[s1 * ROWLEN + lane], a1);
      atomicAdd(&acc[s2 * ROWLEN + lane], a2);
      atomicAdd(&acc[s3 * ROWLEN + lane], a3);
      if (lane < 6) {
        atomicAdd(&acc[s0 * ROWLEN + 64 + lane], b0);
        atomicAdd(&acc[s1 * ROWLEN + 64 + lane], b1);
        atomicAdd(&acc[s2 * ROWLEN + 64 + lane], b2);
        atomicAdd(&acc[s3 * ROWLEN + 64 + lane], b3);
      }
    }
    for (; i < iend; ++i) {
      const int s = sseg[i];
      const float* r = ((s & 1) ? dth_dc : dth_cls) + soff[i];
      atomicAdd(&acc[s * ROWLEN + lane], r[lane]);
      if (lane < 6) atomicAdd(&acc[s * ROWLEN + 64 + lane], r[64 + lane]);
    }
    __syncthreads();
  }

  float* dst = partial + (size_t)b * SEGW;
  for (int i = tid; i < NSEG * ROWLEN; i += 512) dst[i] = acc[i];
  for (int i = tid; i < NSEG; i += 512) dst[NSEG * ROWLEN + i] = cnt[i];
}

// ---------------- K2: reduce partials, 2 deterministic stages ----------------
__global__ __launch_bounds__(256) void seg_reduce1_k(
    const float* __restrict__ partial, float* __restrict__ partial2)
{
  const int j = blockIdx.x * 256 + threadIdx.x;
  if (j >= SEGW) return;
  const int g = blockIdx.y;                  // 0..7
  const float* p = partial + (size_t)g * RCH * SEGW + j;
  float s = 0.f;
  #pragma unroll 7
  for (int b = 0; b < RCH; ++b) s += p[(size_t)b * SEGW];
  partial2[(size_t)g * SEGW + j] = s;
}

__global__ __launch_bounds__(256) void seg_reduce2_k(
    const float* __restrict__ partial2, float* __restrict__ rowsum,
    float* __restrict__ cnt)
{
  const int j = blockIdx.x * 256 + threadIdx.x;
  if (j >= SEGW) return;
  float s = 0.f;
  #pragma unroll
  for (int g = 0; g < 8; ++g) s += partial2[(size_t)g * SEGW + j];
  if (j < NSEG * ROWLEN) rowsum[j] = s;
  else                   cnt[j - NSEG * ROWLEN] = s;
}

// ---------------- K3a: edge_group[s][c] = (rowsum[s] . merge[:,c]) / max(cnt,1) ----
__global__ __launch_bounds__(128) void edge_group_k(
    const float* __restrict__ rowsum, const float* __restrict__ cnt,
    const float* __restrict__ dE, const float* __restrict__ cE,
    float* __restrict__ edge_group)
{
  __shared__ float rs[ROWLEN];
  const int s = blockIdx.x, c = threadIdx.x;
  if (c < ROWLEN) rs[c] = rowsum[s * ROWLEN + c];
  __syncthreads();
  float a = 0.f;
  #pragma unroll
  for (int k = 0; k < DRUG_NUM; ++k) a += rs[k] * dE[k * FEA + c];
  #pragma unroll
  for (int k = DRUG_NUM; k < NUM_NODE; ++k) a += rs[k] * cE[(k - DRUG_NUM) * FEA + c];
  edge_group[s * FEA + c] = a / fmaxf(cnt[s], 1.f);
}

// ---------------- K3b: fc / projections / head-softmax / node_rep ----------------
__global__ __launch_bounds__(128) void node_rep_k(
    const float* __restrict__ edge_group, const float* __restrict__ dE,
    const float* __restrict__ cE, const float* __restrict__ node_proj,
    const float* __restrict__ edge_proj, const float* __restrict__ fc_w,
    const float* __restrict__ fc_b, float* __restrict__ node_rep)
{
  __shared__ float fw[FEA][FEA + 1];
  __shared__ float eg[2][FEA];
  __shared__ float mg[FEA];
  __shared__ float nm[FEA];
  __shared__ float em[2][FEA];
  __shared__ float ef[2][FEA];
  __shared__ float sc[4][2];
  __shared__ float wgt[4][2];

  const int n = blockIdx.x, c = threadIdx.x;
  const int isdrug = (n < DRUG_NUM);
  eg[0][c] = edge_group[(n * 2 + 0) * FEA + c];
  eg[1][c] = edge_group[(n * 2 + 1) * FEA + c];
  mg[c] = isdrug ? dE[n * FEA + c] : cE[(n - DRUG_NUM) * FEA + c];
  for (int r = 0; r < FEA; ++r) fw[r][c] = fc_w[r * FEA + c];
  __syncthreads();

  for (int e = 0; e < 2; ++e) {
    float a = fc_b[c];
    #pragma unroll 8
    for (int k = 0; k < FEA; ++k) a += eg[e][k] * fw[c][k];
    ef[e][c] = fmaxf(a, 0.f);
  }
  {
    const float* P = node_proj + (size_t)(isdrug ? 0 : 1) * FEA * FEA;
    float a = 0.f;
    #pragma unroll 8
    for (int k = 0; k < FEA; ++k) a += mg[k] * P[k * FEA + c];
    nm[c] = a;
  }
  for (int e = 0; e < 2; ++e) {
    const float* P = edge_proj + (size_t)((isdrug ? 0 : 2) + e) * FEA * FEA;
    float a = 0.f;
    #pragma unroll 8
    for (int k = 0; k < FEA; ++k) a += eg[e][k] * P[k * FEA + c];
    em[e][c] = a;
  }
  __syncthreads();

  if (c < 8) {
    const int h = c >> 1, e = c & 1;
    float s = 0.f;
    #pragma unroll
    for (int d = 0; d < 32; ++d) s += nm[h * 32 + d] * em[e][h * 32 + d];
    sc[h][e] = s * 0.17677669529663687f;
  }
  __syncthreads();
  if (c < 2) {
    const int e = c;
    const float mx = fmaxf(fmaxf(sc[0][e], sc[1][e]), fmaxf(sc[2][e], sc[3][e]));
    const float t0 = expf(sc[0][e] - mx), t1 = expf(sc[1][e] - mx);
    const float t2 = expf(sc[2][e] - mx), t3 = expf(sc[3][e] - mx);
    const float inv = 1.f / (t0 + t1 + t2 + t3);
    wgt[0][e] = t0 * inv; wgt[1][e] = t1 * inv;
    wgt[2][e] = t2 * inv; wgt[3][e] = t3 * inv;
  }
  __syncthreads();

  const int h = c >> 5;
  const float v = fmaxf(wgt[h][0] * ef[0][c], 0.f) + fmaxf(wgt[h][1] * ef[1][c], 0.f);
  node_rep[n * FEA + c] = v;
}

// ---------------- K4a: gather + BN (eval) -> emb[8192][384] ----------------
__global__ __launch_bounds__(384) void emb_bn_k(
    const float* __restrict__ node_rep, const int* __restrict__ index,
    const float* __restrict__ gam, const float* __restrict__ bet,
    const float* __restrict__ mean, const float* __restrict__ var,
    float* __restrict__ emb)
{
  const int b = blockIdx.x, j = threadIdx.x;
  const int part = j >> 7, cc = j & 127;
  const int idx = index[b * 3 + part];
  float v = node_rep[idx * FEA + cc];
  v = (v - mean[j]) * rsqrtf(var[j] + 1e-5f) * gam[j] + bet[j];
  emb[(size_t)b * 384 + j] = v;
}

// ---------------- K4b/c: C = lrelu(A @ W^T + bias), 128x64 tile, 8x4 microtile ----
__global__ __launch_bounds__(256) void gemm_nt_k(
    const float* __restrict__ A,     // [M,K]
    const float* __restrict__ W,     // [N,K]
    const float* __restrict__ bias,  // [N]
    float* __restrict__ C,           // [M,N]
    int M, int N, int K, int do_lrelu)
{
  __shared__ float As[16][132];
  __shared__ float Ws[16][68];
  const int tid = threadIdx.x;
  const int tx = tid & 15, ty = tid >> 4;        // compute layout 16x16
  const int row0 = blockIdx.y * 128, col0 = blockIdx.x * 64;
  const int lra = tid >> 1, lka = (tid & 1) * 8; // A-load: 128 rows x 2
  const int lrw = tid >> 2, lkw = (tid & 3) * 4; // W-load: 64 rows x 4
  float acc[8][4] = {{0.f}};

  for (int k0 = 0; k0 < K; k0 += 16) {
    const float4 av0 = *(const float4*)(A + (size_t)(row0 + lra) * K + k0 + lka);
    const float4 av1 = *(const float4*)(A + (size_t)(row0 + lra) * K + k0 + lka + 4);
    const float4 wv  = *(const float4*)(W + (size_t)(col0 + lrw) * K + k0 + lkw);
    __syncthreads();
    As[lka + 0][lra] = av0.x; As[lka + 1][lra] = av0.y; As[lka + 2][lra] = av0.z; As[lka + 3][lra] = av0.w;
    As[lka + 4][lra] = av1.x; As[lka + 5][lra] = av1.y; As[lka + 6][lra] = av1.z; As[lka + 7][lra] = av1.w;
    Ws[lkw + 0][lrw] = wv.x;  Ws[lkw + 1][lrw] = wv.y;  Ws[lkw + 2][lrw] = wv.z;  Ws[lkw + 3][lrw] = wv.w;
    __syncthreads();
    #pragma unroll
    for (int kk = 0; kk < 16; ++kk) {
      const float4 alo = *(const float4*)&As[kk][ty * 8];
      const float4 ahi = *(const float4*)&As[kk][ty * 8 + 4];
      const float4 b   = *(const float4*)&Ws[kk][tx * 4];
      acc[0][0] += alo.x*b.x; acc[0][1] += alo.x*b.y; acc[0][2] += alo.x*b.z; acc[0][3] += alo.x*b.w;
      acc[1][0] += alo.y*b.x; acc[1][1] += alo.y*b.y; acc[1][2] += alo.y*b.z; acc[1][3] += alo.y*b.w;
      acc[2][0] += alo.z*b.x; acc[2][1] += alo.z*b.y; acc[2][2] += alo.z*b.z; acc[2][3] += alo.z*b.w;
      acc[3][0] += alo.w*b.x; acc[3][1] += alo.w*b.y; acc[3][2] += alo.w*b.z; acc[3][3] += alo.w*b.w;
      acc[4][0] += ahi.x*b.x; acc[4][1] += ahi.x*b.y; acc[4][2] += ahi.x*b.z; acc[4][3] += ahi.x*b.w;
      acc[5][0] += ahi.y*b.x; acc[5][1] += ahi.y*b.y; acc[5][2] += ahi.y*b.z; acc[5][3] += ahi.y*b.w;
      acc[6][0] += ahi.z*b.x; acc[6][1] += ahi.z*b.y; acc[6][2] += ahi.z*b.z; acc[6][3] += ahi.z*b.w;
      acc[7][0] += ahi.w*b.x; acc[7][1] += ahi.w*b.y; acc[7][2] += ahi.w*b.z; acc[7][3] += ahi.w*b.w;
    }
  }

  const float4 bv = *(const float4*)(bias + col0 + tx * 4);
  #pragma unroll
  for (int i = 0; i < 8; ++i) {
    const int r = row0 + ty * 8 + i;
    float4 o;
    o.x = acc[i][0] + bv.x; o.y = acc[i][1] + bv.y;
    o.z = acc[i][2] + bv.z; o.w = acc[i][3] + bv.w;
    if (do_lrelu) {
      o.x = o.x > 0.f ? o.x : 0.5f * o.x; o.y = o.y > 0.f ? o.y : 0.5f * o.y;
      o.z = o.z > 0.f ? o.z : 0.5f * o.z; o.w = o.w > 0.f ? o.w : 0.5f * o.w;
    }
    *(float4*)(C + (size_t)r * N + col0 + tx * 4) = o;
  }
}

// ---------------- K4d: out0 = sigmoid(h @ w3 + b3) ----------------
__global__ __launch_bounds__(256) void lin3_k(
    const float* __restrict__ H, const float* __restrict__ w3,
    const float* __restrict__ b3, float* __restrict__ out)
{
  const int row = blockIdx.x * 4 + (threadIdx.x >> 6);
  const int lane = threadIdx.x & 63;
  const float4 h = *(const float4*)(H + (size_t)row * 256 + lane * 4);
  const float4 w = *(const float4*)(w3 + lane * 4);
  float v = h.x * w.x + h.y * w.y + h.z * w.z + h.w * w.w;
  #pragma unroll
  for (int off = 32; off; off >>= 1) v += __shfl_down(v, off);
  if (lane == 0) out[row] = 1.f / (1.f + expf(-(v + b3[0])));
}

extern "C" void kernel_launch(void* const* d_in, const int* in_sizes, int n_in,
                              void* d_out, int out_size, void* d_ws, size_t ws_size,
                              hipStream_t stream) {
  const float* dth_cls  = (const float*)d_in[2];
  const float* dth_dc   = (const float*)d_in[3];
  const int*   he_node  = (const int*)d_in[4];
  const int*   he_edge  = (const int*)d_in[5];
  const int*   index    = (const int*)d_in[7];
  const float* dE       = (const float*)d_in[8];
  const float* cE       = (const float*)d_in[9];
  const float* node_proj= (const float*)d_in[10];
  const float* edge_proj= (const float*)d_in[11];
  const float* fc_w     = (const float*)d_in[12];
  const float* fc_b     = (const float*)d_in[13];
  const float* bn_g     = (const float*)d_in[14];
  const float* bn_b     = (const float*)d_in[15];
  const float* bn_m     = (const float*)d_in[16];
  const float* bn_v     = (const float*)d_in[17];
  const float* w1       = (const float*)d_in[18];
  const float* b1       = (const float*)d_in[19];
  const float* w2       = (const float*)d_in[20];
  const float* b2       = (const float*)d_in[21];
  const float* w3       = (const float*)d_in[22];
  const float* b3       = (const float*)d_in[23];

  float* out0 = (float*)d_out;
  float* hout = out0 + BATCH;

  float* ws        = (float*)d_ws;
  float* rowsum    = ws + 0;                  // 9800
  float* cnt       = ws + 9856;               // 140
  float* edge_group= ws + 10048;              // 140*128 -> end 27968
  float* node_rep  = ws + 28032;              // 70*128  -> end 36992
  float* emb       = ws + 37056;              // 8192*384 -> end 3182784
  float* h1        = ws + 3182784;            // 8192*512 -> end 7377088
  float* partial   = ws + 37056;              // 728*9940 -> end 7273376 (aliases emb/h1, consumed first)
  float* partial2  = ws + 7273376;            // 8*9940   -> end 7352896 (consumed before h1 written)

  seg_partial_k<<<NB1, 512, 0, stream>>>(dth_cls, dth_dc, he_node, he_edge, partial);
  seg_reduce1_k<<<dim3((SEGW + 255) / 256, 8), 256, 0, stream>>>(partial, partial2);
  seg_reduce2_k<<<(SEGW + 255) / 256, 256, 0, stream>>>(partial2, rowsum, cnt);
  edge_group_k<<<NSEG, 128, 0, stream>>>(rowsum, cnt, dE, cE, edge_group);
  node_rep_k<<<NUM_NODE, 128, 0, stream>>>(edge_group, dE, cE, node_proj, edge_proj,
                                           fc_w, fc_b, node_rep);
  emb_bn_k<<<BATCH, 384, 0, stream>>>(node_rep, index, bn_g, bn_b, bn_m, bn_v, emb);
  gemm_nt_k<<<dim3(512 / 64, BATCH / 128), 256, 0, stream>>>(emb, w1, b1, h1,
                                                             BATCH, 512, 384, 1);
  gemm_nt_k<<<dim3(256 / 64, BATCH / 128), 256, 0, stream>>>(h1, w2, b2, hout,
                                                             BATCH, 256, 512, 1);
  lin3_k<<<BATCH / 4, 256, 0, stream>>>(hout, w3, b3, out0);
}

// Round 3
// 188.836 us; speedup vs baseline: 1.8869x; 1.8869x over previous
//
#include <hip/hip_runtime.h>

#define NUM_CLS   131072
#define NUM_NODE  70
#define DRUG_NUM  38
#define NSEG      140
#define ROWLEN    70
#define FEA       128
#define MTOT      524288
#define BATCH     8192
#define NB_H      512                 // histogram / scatter blocks (1024 entries each)
#define NCHUNK    32                  // accumulate chunks per segment

// ---------------- P1: per-block segment histogram ----------------
__global__ __launch_bounds__(256) void hist_k(
    const int* __restrict__ he_node, const int* __restrict__ he_edge,
    int* __restrict__ hist_t)        // [NSEG][NB_H]
{
  __shared__ int h[NSEG];
  const int tid = threadIdx.x;
  if (tid < NSEG) h[tid] = 0;
  __syncthreads();
  const int base = blockIdx.x * 1024;
  #pragma unroll
  for (int t = 0; t < 4; ++t) {
    const int e = base + t * 256 + tid;
    const int seg = he_node[e] * 2 + (he_edge[e] >= NUM_CLS);
    atomicAdd(&h[seg], 1);
  }
  __syncthreads();
  if (tid < NSEG) hist_t[tid * NB_H + blockIdx.x] = h[tid];
}

// ---------------- P2a: per-seg exclusive scan over blocks ----------------
__global__ __launch_bounds__(512) void scan_blocks_k(
    const int* __restrict__ hist_t, int* __restrict__ scan_t,
    int* __restrict__ seg_total)
{
  __shared__ int v[NB_H];
  const int s = blockIdx.x, tid = threadIdx.x;
  const int x0 = hist_t[s * NB_H + tid];
  v[tid] = x0;
  __syncthreads();
  for (int off = 1; off < NB_H; off <<= 1) {
    int y = (tid >= off) ? v[tid - off] : 0;
    __syncthreads();
    v[tid] += y;
    __syncthreads();
  }
  scan_t[s * NB_H + tid] = v[tid] - x0;     // exclusive
  if (tid == NB_H - 1) seg_total[s] = v[tid];
}

// ---------------- P2b: segment bases ----------------
__global__ __launch_bounds__(256) void base_k(
    const int* __restrict__ seg_total, int* __restrict__ seg_base,
    float* __restrict__ cnt_f)
{
  __shared__ int tot[NSEG];
  __shared__ int bs[NSEG + 1];
  const int tid = threadIdx.x;
  if (tid < NSEG) tot[tid] = seg_total[tid];
  __syncthreads();
  if (tid == 0) {
    int run = 0;
    for (int s = 0; s < NSEG; ++s) { bs[s] = run; run += tot[s]; }
    bs[NSEG] = run;
  }
  __syncthreads();
  if (tid < NSEG) { seg_base[tid] = bs[tid]; cnt_f[tid] = (float)tot[tid]; }
  if (tid == NSEG) seg_base[NSEG] = bs[NSEG];
}

// ---------------- P3: scatter row-offsets into seg-sorted order ----------------
__global__ __launch_bounds__(256) void scatter_k(
    const int* __restrict__ he_node, const int* __restrict__ he_edge,
    const int* __restrict__ scan_t, const int* __restrict__ seg_base,
    int* __restrict__ sorted_off)
{
  __shared__ int rank[NSEG];
  __shared__ int base[NSEG];
  const int tid = threadIdx.x;
  if (tid < NSEG) {
    rank[tid] = 0;
    base[tid] = seg_base[tid] + scan_t[tid * NB_H + blockIdx.x];
  }
  __syncthreads();
  const int e0 = blockIdx.x * 1024;
  #pragma unroll
  for (int t = 0; t < 4; ++t) {
    const int e = e0 + t * 256 + tid;
    const int node = he_node[e];
    const int edge = he_edge[e];
    const int isdc = (edge >= NUM_CLS);
    const int seg  = node * 2 + isdc;
    const int off  = (isdc ? edge - NUM_CLS : edge) * ROWLEN;
    const int r = atomicAdd(&rank[seg], 1);
    sorted_off[base[seg] + r] = off;
  }
}

// ---------------- P4: register-accumulate rows per (seg, chunk) ----------------
__global__ __launch_bounds__(256) void seg_acc_k(
    const float* __restrict__ dth_cls, const float* __restrict__ dth_dc,
    const int* __restrict__ sorted_off, const int* __restrict__ seg_base,
    float* __restrict__ partial)     // [NSEG][NCHUNK][ROWLEN]
{
  const int s = blockIdx.x;
  const int wid = threadIdx.x >> 6, lane = threadIdx.x & 63;
  const int chunk = blockIdx.y * 4 + wid;
  const int b0 = seg_base[s];
  const int n  = seg_base[s + 1] - b0;
  const int c0 = b0 + (int)(((long long)n * chunk) >> 5);
  const int c1 = b0 + (int)(((long long)n * (chunk + 1)) >> 5);
  const float* __restrict__ T = (s & 1) ? dth_dc : dth_cls;

  float acc[ROWLEN];
  #pragma unroll
  for (int c = 0; c < ROWLEN; ++c) acc[c] = 0.f;

  for (int i = c0 + lane; i < c1; i += 64) {   // lane-per-entry, coalesced index read
    const float2* __restrict__ r = (const float2*)(T + sorted_off[i]);
    #pragma unroll
    for (int c = 0; c < 35; ++c) {             // 35 independent 8B loads, no LDS
      const float2 v = r[c];
      acc[2 * c]     += v.x;
      acc[2 * c + 1] += v.y;
    }
  }

  #pragma unroll
  for (int m = 1; m < 64; m <<= 1) {
    #pragma unroll
    for (int c = 0; c < ROWLEN; ++c) acc[c] += __shfl_xor(acc[c], m, 64);
  }
  if (lane == 0) {
    float* dst = partial + ((size_t)s * NCHUNK + chunk) * ROWLEN;
    #pragma unroll
    for (int c = 0; c < ROWLEN; ++c) dst[c] = acc[c];
  }
}

// ---------------- P5: reduce chunk partials -> rowsum ----------------
__global__ __launch_bounds__(128) void seg_fin_k(
    const float* __restrict__ partial, float* __restrict__ rowsum)
{
  const int s = blockIdx.x, c = threadIdx.x;
  if (c >= ROWLEN) return;
  float v = 0.f;
  #pragma unroll
  for (int k = 0; k < NCHUNK; ++k)
    v += partial[((size_t)s * NCHUNK + k) * ROWLEN + c];
  rowsum[s * ROWLEN + c] = v;
}

// ---------------- K3a: edge_group[s][c] = (rowsum[s] . merge[:,c]) / max(cnt,1) ----
__global__ __launch_bounds__(128) void edge_group_k(
    const float* __restrict__ rowsum, const float* __restrict__ cnt,
    const float* __restrict__ dE, const float* __restrict__ cE,
    float* __restrict__ edge_group)
{
  __shared__ float rs[ROWLEN];
  const int s = blockIdx.x, c = threadIdx.x;
  if (c < ROWLEN) rs[c] = rowsum[s * ROWLEN + c];
  __syncthreads();
  float a = 0.f;
  #pragma unroll
  for (int k = 0; k < DRUG_NUM; ++k) a += rs[k] * dE[k * FEA + c];
  #pragma unroll
  for (int k = DRUG_NUM; k < NUM_NODE; ++k) a += rs[k] * cE[(k - DRUG_NUM) * FEA + c];
  edge_group[s * FEA + c] = a / fmaxf(cnt[s], 1.f);
}

// ---------------- K3b: fc / projections / head-softmax / node_rep ----------------
__global__ __launch_bounds__(128) void node_rep_k(
    const float* __restrict__ edge_group, const float* __restrict__ dE,
    const float* __restrict__ cE, const float* __restrict__ node_proj,
    const float* __restrict__ edge_proj, const float* __restrict__ fc_w,
    const float* __restrict__ fc_b, float* __restrict__ node_rep)
{
  __shared__ float fw[FEA][FEA + 1];
  __shared__ float eg[2][FEA];
  __shared__ float mg[FEA];
  __shared__ float nm[FEA];
  __shared__ float em[2][FEA];
  __shared__ float ef[2][FEA];
  __shared__ float sc[4][2];
  __shared__ float wgt[4][2];

  const int n = blockIdx.x, c = threadIdx.x;
  const int isdrug = (n < DRUG_NUM);
  eg[0][c] = edge_group[(n * 2 + 0) * FEA + c];
  eg[1][c] = edge_group[(n * 2 + 1) * FEA + c];
  mg[c] = isdrug ? dE[n * FEA + c] : cE[(n - DRUG_NUM) * FEA + c];
  for (int r = 0; r < FEA; ++r) fw[r][c] = fc_w[r * FEA + c];
  __syncthreads();

  for (int e = 0; e < 2; ++e) {
    float a = fc_b[c];
    #pragma unroll 8
    for (int k = 0; k < FEA; ++k) a += eg[e][k] * fw[c][k];
    ef[e][c] = fmaxf(a, 0.f);
  }
  {
    const float* P = node_proj + (size_t)(isdrug ? 0 : 1) * FEA * FEA;
    float a = 0.f;
    #pragma unroll 8
    for (int k = 0; k < FEA; ++k) a += mg[k] * P[k * FEA + c];
    nm[c] = a;
  }
  for (int e = 0; e < 2; ++e) {
    const float* P = edge_proj + (size_t)((isdrug ? 0 : 2) + e) * FEA * FEA;
    float a = 0.f;
    #pragma unroll 8
    for (int k = 0; k < FEA; ++k) a += eg[e][k] * P[k * FEA + c];
    em[e][c] = a;
  }
  __syncthreads();

  if (c < 8) {
    const int h = c >> 1, e = c & 1;
    float s = 0.f;
    #pragma unroll
    for (int d = 0; d < 32; ++d) s += nm[h * 32 + d] * em[e][h * 32 + d];
    sc[h][e] = s * 0.17677669529663687f;
  }
  __syncthreads();
  if (c < 2) {
    const int e = c;
    const float mx = fmaxf(fmaxf(sc[0][e], sc[1][e]), fmaxf(sc[2][e], sc[3][e]));
    const float t0 = expf(sc[0][e] - mx), t1 = expf(sc[1][e] - mx);
    const float t2 = expf(sc[2][e] - mx), t3 = expf(sc[3][e] - mx);
    const float inv = 1.f / (t0 + t1 + t2 + t3);
    wgt[0][e] = t0 * inv; wgt[1][e] = t1 * inv;
    wgt[2][e] = t2 * inv; wgt[3][e] = t3 * inv;
  }
  __syncthreads();

  const int h = c >> 5;
  const float v = fmaxf(wgt[h][0] * ef[0][c], 0.f) + fmaxf(wgt[h][1] * ef[1][c], 0.f);
  node_rep[n * FEA + c] = v;
}

// ---------------- K4a: gather + BN (eval) -> emb[8192][384] ----------------
__global__ __launch_bounds__(384) void emb_bn_k(
    const float* __restrict__ node_rep, const int* __restrict__ index,
    const float* __restrict__ gam, const float* __restrict__ bet,
    const float* __restrict__ mean, const float* __restrict__ var,
    float* __restrict__ emb)
{
  const int b = blockIdx.x, j = threadIdx.x;
  const int part = j >> 7, cc = j & 127;
  const int idx = index[b * 3 + part];
  float v = node_rep[idx * FEA + cc];
  v = (v - mean[j]) * rsqrtf(var[j] + 1e-5f) * gam[j] + bet[j];
  emb[(size_t)b * 384 + j] = v;
}

// ---------------- K4b/c: C = lrelu(A @ W^T + bias), 128x64 tile, 8x4 microtile ----
__global__ __launch_bounds__(256) void gemm_nt_k(
    const float* __restrict__ A, const float* __restrict__ W,
    const float* __restrict__ bias, float* __restrict__ C,
    int M, int N, int K, int do_lrelu)
{
  __shared__ float As[16][132];
  __shared__ float Ws[16][68];
  const int tid = threadIdx.x;
  const int tx = tid & 15, ty = tid >> 4;
  const int row0 = blockIdx.y * 128, col0 = blockIdx.x * 64;
  const int lra = tid >> 1, lka = (tid & 1) * 8;
  const int lrw = tid >> 2, lkw = (tid & 3) * 4;
  float acc[8][4] = {{0.f}};

  for (int k0 = 0; k0 < K; k0 += 16) {
    const float4 av0 = *(const float4*)(A + (size_t)(row0 + lra) * K + k0 + lka);
    const float4 av1 = *(const float4*)(A + (size_t)(row0 + lra) * K + k0 + lka + 4);
    const float4 wv  = *(const float4*)(W + (size_t)(col0 + lrw) * K + k0 + lkw);
    __syncthreads();
    As[lka + 0][lra] = av0.x; As[lka + 1][lra] = av0.y; As[lka + 2][lra] = av0.z; As[lka + 3][lra] = av0.w;
    As[lka + 4][lra] = av1.x; As[lka + 5][lra] = av1.y; As[lka + 6][lra] = av1.z; As[lka + 7][lra] = av1.w;
    Ws[lkw + 0][lrw] = wv.x;  Ws[lkw + 1][lrw] = wv.y;  Ws[lkw + 2][lrw] = wv.z;  Ws[lkw + 3][lrw] = wv.w;
    __syncthreads();
    #pragma unroll
    for (int kk = 0; kk < 16; ++kk) {
      const float4 alo = *(const float4*)&As[kk][ty * 8];
      const float4 ahi = *(const float4*)&As[kk][ty * 8 + 4];
      const float4 b   = *(const float4*)&Ws[kk][tx * 4];
      acc[0][0] += alo.x*b.x; acc[0][1] += alo.x*b.y; acc[0][2] += alo.x*b.z; acc[0][3] += alo.x*b.w;
      acc[1][0] += alo.y*b.x; acc[1][1] += alo.y*b.y; acc[1][2] += alo.y*b.z; acc[1][3] += alo.y*b.w;
      acc[2][0] += alo.z*b.x; acc[2][1] += alo.z*b.y; acc[2][2] += alo.z*b.z; acc[2][3] += alo.z*b.w;
      acc[3][0] += alo.w*b.x; acc[3][1] += alo.w*b.y; acc[3][2] += alo.w*b.z; acc[3][3] += alo.w*b.w;
      acc[4][0] += ahi.x*b.x; acc[4][1] += ahi.x*b.y; acc[4][2] += ahi.x*b.z; acc[4][3] += ahi.x*b.w;
      acc[5][0] += ahi.y*b.x; acc[5][1] += ahi.y*b.y; acc[5][2] += ahi.y*b.z; acc[5][3] += ahi.y*b.w;
      acc[6][0] += ahi.z*b.x; acc[6][1] += ahi.z*b.y; acc[6][2] += ahi.z*b.z; acc[6][3] += ahi.z*b.w;
      acc[7][0] += ahi.w*b.x; acc[7][1] += ahi.w*b.y; acc[7][2] += ahi.w*b.z; acc[7][3] += ahi.w*b.w;
    }
  }

  const float4 bv = *(const float4*)(bias + col0 + tx * 4);
  #pragma unroll
  for (int i = 0; i < 8; ++i) {
    const int r = row0 + ty * 8 + i;
    float4 o;
    o.x = acc[i][0] + bv.x; o.y = acc[i][1] + bv.y;
    o.z = acc[i][2] + bv.z; o.w = acc[i][3] + bv.w;
    if (do_lrelu) {
      o.x = o.x > 0.f ? o.x : 0.5f * o.x; o.y = o.y > 0.f ? o.y : 0.5f * o.y;
      o.z = o.z > 0.f ? o.z : 0.5f * o.z; o.w = o.w > 0.f ? o.w : 0.5f * o.w;
    }
    *(float4*)(C + (size_t)r * N + col0 + tx * 4) = o;
  }
}

// ---------------- K4d: out0 = sigmoid(h @ w3 + b3) ----------------
__global__ __launch_bounds__(256) void lin3_k(
    const float* __restrict__ H, const float* __restrict__ w3,
    const float* __restrict__ b3, float* __restrict__ out)
{
  const int row = blockIdx.x * 4 + (threadIdx.x >> 6);
  const int lane = threadIdx.x & 63;
  const float4 h = *(const float4*)(H + (size_t)row * 256 + lane * 4);
  const float4 w = *(const float4*)(w3 + lane * 4);
  float v = h.x * w.x + h.y * w.y + h.z * w.z + h.w * w.w;
  #pragma unroll
  for (int off = 32; off; off >>= 1) v += __shfl_down(v, off);
  if (lane == 0) out[row] = 1.f / (1.f + expf(-(v + b3[0])));
}

extern "C" void kernel_launch(void* const* d_in, const int* in_sizes, int n_in,
                              void* d_out, int out_size, void* d_ws, size_t ws_size,
                              hipStream_t stream) {
  const float* dth_cls  = (const float*)d_in[2];
  const float* dth_dc   = (const float*)d_in[3];
  const int*   he_node  = (const int*)d_in[4];
  const int*   he_edge  = (const int*)d_in[5];
  const int*   index    = (const int*)d_in[7];
  const float* dE       = (const float*)d_in[8];
  const float* cE       = (const float*)d_in[9];
  const float* node_proj= (const float*)d_in[10];
  const float* edge_proj= (const float*)d_in[11];
  const float* fc_w     = (const float*)d_in[12];
  const float* fc_b     = (const float*)d_in[13];
  const float* bn_g     = (const float*)d_in[14];
  const float* bn_b     = (const float*)d_in[15];
  const float* bn_m     = (const float*)d_in[16];
  const float* bn_v     = (const float*)d_in[17];
  const float* w1       = (const float*)d_in[18];
  const float* b1       = (const float*)d_in[19];
  const float* w2       = (const float*)d_in[20];
  const float* b2       = (const float*)d_in[21];
  const float* w3       = (const float*)d_in[22];
  const float* b3       = (const float*)d_in[23];

  float* out0 = (float*)d_out;
  float* hout = out0 + BATCH;

  float* ws        = (float*)d_ws;
  float* rowsum    = ws + 0;                  // 9800
  float* cnt_f     = ws + 9856;               // 140
  float* edge_group= ws + 10048;              // -> 27968
  float* node_rep  = ws + 28032;              // -> 36992
  float* emb       = ws + 37056;              // -> 3182784
  float* h1        = ws + 3182784;            // -> 7377088
  // scratch aliased inside emb span (all consumed before emb_bn_k writes emb):
  int*   sorted_off= (int*)(ws + 37056);      // 524288 -> 561344
  int*   hist_t    = (int*)(ws + 561344);     // 71680  -> 633024
  int*   scan_t    = (int*)(ws + 633024);     // 71680  -> 704704
  int*   seg_total = (int*)(ws + 704704);     // 140    -> 704844
  int*   seg_base  = (int*)(ws + 704844);     // 141    -> 704985
  float* partial   = ws + 704992;             // 313600 -> 1018592

  hist_k<<<NB_H, 256, 0, stream>>>(he_node, he_edge, hist_t);
  scan_blocks_k<<<NSEG, NB_H, 0, stream>>>(hist_t, scan_t, seg_total);
  base_k<<<1, 256, 0, stream>>>(seg_total, seg_base, cnt_f);
  scatter_k<<<NB_H, 256, 0, stream>>>(he_node, he_edge, scan_t, seg_base, sorted_off);
  seg_acc_k<<<dim3(NSEG, NCHUNK / 4), 256, 0, stream>>>(dth_cls, dth_dc, sorted_off,
                                                        seg_base, partial);
  seg_fin_k<<<NSEG, 128, 0, stream>>>(partial, rowsum);
  edge_group_k<<<NSEG, 128, 0, stream>>>(rowsum, cnt_f, dE, cE, edge_group);
  node_rep_k<<<NUM_NODE, 128, 0, stream>>>(edge_group, dE, cE, node_proj, edge_proj,
                                           fc_w, fc_b, node_rep);
  emb_bn_k<<<BATCH, 384, 0, stream>>>(node_rep, index, bn_g, bn_b, bn_m, bn_v, emb);
  gemm_nt_k<<<dim3(512 / 64, BATCH / 128), 256, 0, stream>>>(emb, w1, b1, h1,
                                                             BATCH, 512, 384, 1);
  gemm_nt_k<<<dim3(256 / 64, BATCH / 128), 256, 0, stream>>>(h1, w2, b2, hout,
                                                             BATCH, 256, 512, 1);
  lin3_k<<<BATCH / 4, 256, 0, stream>>>(hout, w3, b3, out0);
}